// Round 1
// baseline (5111.213 us; speedup 1.0000x reference)
//
#include <hip/hip_runtime.h>
#include <hip/hip_bf16.h>
#include <stdint.h>

#define DEV __device__ __forceinline__

typedef __attribute__((ext_vector_type(8))) short short8;   // 8 bf16 (4 VGPRs)
typedef __attribute__((ext_vector_type(4))) float floatx4;  // MFMA acc

DEV unsigned short f2bf(float f) {  // round-to-nearest-even fp32 -> bf16
  union { float f; unsigned u; } v; v.f = f;
  return (unsigned short)((v.u + 0x7fffu + ((v.u >> 16) & 1u)) >> 16);
}
DEV float bf2f(unsigned short s) {
  union { unsigned u; float f; } v; v.u = ((unsigned)s) << 16; return v.f;
}
DEV float sigmoid_f(float x) { return 1.0f / (1.0f + __expf(-x)); }
DEV float tanh_f(float x) { return 1.0f - 2.0f / (__expf(2.0f * x) + 1.0f); }

// async global->LDS, 16B per lane; LDS dest = wave-uniform base + lane*16
DEV void glds16(const unsigned short* g, unsigned short* l) {
  __builtin_amdgcn_global_load_lds(
      (const __attribute__((address_space(1))) unsigned int*)g,
      (__attribute__((address_space(3))) unsigned int*)l, 16, 0, 0);
}

// ---------------------------------------------------------------------------
// Shared 128x128 GEMM core: C[128][128] = A[tileM..+128][0..1024) * B^T
// A,B bf16, K-contiguous rows of length 1024. 4 waves, each 64x64 (4x4 frags
// of 16x16x32). LDS in fragment-gather order: frag f at f*1024B, lane l at
// +l*16B -> ds_read_b128 lane-linear (conflict-free), no repack.
// Double-buffered: glds prefetch of k+32 issued after barrier, drained by the
// next barrier's implicit vmcnt(0) -> latency hidden behind MFMA.
// ---------------------------------------------------------------------------
DEV void gemm128(const unsigned short* __restrict__ A,
                 const unsigned short* __restrict__ B,
                 int tileM, int tileN, floatx4 (&acc)[4][4]) {
  __shared__ __align__(16) unsigned short lds[2][2][4096];  // [buf][A/B][8 frags]
  const int tid = threadIdx.x;
  const int w = tid >> 6, l = tid & 63;
  const int l15 = l & 15, l4 = l >> 4;
  const int wm = w >> 1, wn = w & 1;

  floatx4 z = {0.f, 0.f, 0.f, 0.f};
#pragma unroll
  for (int i = 0; i < 4; i++)
#pragma unroll
    for (int j = 0; j < 4; j++) acc[i][j] = z;

  // per-lane gather addresses: frag f, lane l -> row tile+f*16+(l&15), k=(l>>4)*8
  const unsigned short* ga0 = A + (size_t)(tileM + w * 16 + l15) * 1024 + l4 * 8;
  const unsigned short* ga1 = ga0 + 64 * 1024;
  const unsigned short* gb0 = B + (size_t)(tileN + w * 16 + l15) * 1024 + l4 * 8;
  const unsigned short* gb1 = gb0 + 64 * 1024;

  // prologue: stage k=0 into buf 0
  glds16(ga0, &lds[0][0][w * 512]);
  glds16(ga1, &lds[0][0][(w + 4) * 512]);
  glds16(gb0, &lds[0][1][w * 512]);
  glds16(gb1, &lds[0][1][(w + 4) * 512]);

#pragma unroll 2
  for (int k0 = 0; k0 < 1024; k0 += 32) {
    const int buf = (k0 >> 5) & 1;
    __syncthreads();  // waits vmcnt(0): staged buf ready; prev reads of buf^1 done
    const int kn = k0 + 32;
    if (kn < 1024) {  // prefetch next chunk into the other buffer
      const int nb = buf ^ 1;
      glds16(ga0 + kn, &lds[nb][0][w * 512]);
      glds16(ga1 + kn, &lds[nb][0][(w + 4) * 512]);
      glds16(gb0 + kn, &lds[nb][1][w * 512]);
      glds16(gb1 + kn, &lds[nb][1][(w + 4) * 512]);
    }
    short8 af[4], bfr[4];
    const unsigned short* lA = &lds[buf][0][wm * 2048];
    const unsigned short* lB = &lds[buf][1][wn * 2048];
#pragma unroll
    for (int i = 0; i < 4; i++) af[i] = *(const short8*)(lA + i * 512 + l * 8);
#pragma unroll
    for (int j = 0; j < 4; j++) bfr[j] = *(const short8*)(lB + j * 512 + l * 8);
#pragma unroll
    for (int i = 0; i < 4; i++)
#pragma unroll
      for (int j = 0; j < 4; j++)
        acc[i][j] = __builtin_amdgcn_mfma_f32_16x16x32_bf16(af[i], bfr[j], acc[i][j], 0, 0, 0);
  }
}

// C/D layout (m89-verified): col = lane&15, row = (lane>>4)*4 + reg
#define EPILOGUE_INDICES                                   \
  const int tid = threadIdx.x;                             \
  const int w = tid >> 6, l = tid & 63;                    \
  const int l15 = l & 15, l4 = l >> 4;                     \
  const int wm = w >> 1, wn = w & 1;

// ---------------------------------------------------------------------------
// K1: precompute x-projections. A = Xbf [16384][1024] (row = b*64+t),
// B = Wx_cat [3072][1024] (rows: W_iu | W_ir | W_i).
// n<2048: XPur[t][b][n] = bf16(acc + folded gate biases)
// n>=2048: out[b][t][n'] = acc + b_i   (XPi staged fp32 inside d_out)
// ---------------------------------------------------------------------------
__global__ __launch_bounds__(256) void k_pre(
    const unsigned short* __restrict__ Xbf, const unsigned short* __restrict__ Wx,
    unsigned short* __restrict__ XPur, float* __restrict__ out,
    const float* __restrict__ b_iu, const float* __restrict__ b_hu,
    const float* __restrict__ b_ir, const float* __restrict__ b_hr,
    const float* __restrict__ b_i) {
  const int tileN = blockIdx.x * 128;  // 0..2944
  const int tileM = blockIdx.y * 128;  // 0..16256
  floatx4 acc[4][4];
  gemm128(Xbf, Wx, tileM, tileN, acc);
  EPILOGUE_INDICES
#pragma unroll
  for (int i = 0; i < 4; i++)
#pragma unroll
    for (int j = 0; j < 4; j++) {
      const int col = tileN + wn * 64 + j * 16 + l15;
      const int rbase = tileM + wm * 64 + i * 16 + l4 * 4;
#pragma unroll
      for (int r = 0; r < 4; r++) {
        const int row = rbase + r;
        const float v = acc[i][j][r];
        if (col < 2048) {
          const float bias = (col < 1024) ? (b_iu[col] + b_hu[col])
                                          : (b_ir[col - 1024] + b_hr[col - 1024]);
          const int b = row >> 6, t = row & 63;
          XPur[(size_t)((t << 8) | b) * 2048 + col] = f2bf(v + bias);
        } else {
          out[(size_t)row * 1024 + (col - 2048)] = v + b_i[col - 2048];
        }
      }
    }
}

// ---------------------------------------------------------------------------
// K3 (phase A, step t): G = hbf @ [W_hu;W_hr]^T.  n<1024 -> u = sigmoid(pre);
// else r = sigmoid(pre), rh = bf16(r*h). pre = G + XPur[t] (biases folded).
// ---------------------------------------------------------------------------
__global__ __launch_bounds__(256) void k_gates(
    const unsigned short* __restrict__ hbf, const unsigned short* __restrict__ Whh,
    const unsigned short* __restrict__ XPur_t, float* __restrict__ u,
    const float* __restrict__ h, unsigned short* __restrict__ rh) {
  const int tileN = blockIdx.x * 128;  // 0..1920
  const int tileM = blockIdx.y * 128;  // 0 or 128
  floatx4 acc[4][4];
  gemm128(hbf, Whh, tileM, tileN, acc);
  EPILOGUE_INDICES
#pragma unroll
  for (int i = 0; i < 4; i++)
#pragma unroll
    for (int j = 0; j < 4; j++) {
      const int col = tileN + wn * 64 + j * 16 + l15;
      const int rbase = tileM + wm * 64 + i * 16 + l4 * 4;
#pragma unroll
      for (int r = 0; r < 4; r++) {
        const int row = rbase + r;
        const float pre = acc[i][j][r] + bf2f(XPur_t[(size_t)row * 2048 + col]);
        if (col < 1024) {
          u[row * 1024 + col] = sigmoid_f(pre);
        } else {
          const int nc = col - 1024;
          const float rr = sigmoid_f(pre);
          rh[row * 1024 + nc] = f2bf(rr * h[row * 1024 + nc]);
        }
      }
    }
}

// ---------------------------------------------------------------------------
// K4 (phase B, step t): P = rh @ W_h^T; cand = tanh(P + XPi + b_h);
// h_new = u*h + (1-u)*cand -> d_out[b][t][:], h (fp32), hbf (bf16).
// Reads XPi from the same d_out element it overwrites (same thread -> safe).
// ---------------------------------------------------------------------------
__global__ __launch_bounds__(256) void k_cand(
    const unsigned short* __restrict__ rh, const unsigned short* __restrict__ Wh,
    float* __restrict__ out, float* __restrict__ h, unsigned short* __restrict__ hbf,
    const float* __restrict__ u, const float* __restrict__ b_h, int t) {
  const int tileN = blockIdx.x * 128;  // 0..896
  const int tileM = blockIdx.y * 128;
  floatx4 acc[4][4];
  gemm128(rh, Wh, tileM, tileN, acc);
  EPILOGUE_INDICES
#pragma unroll
  for (int i = 0; i < 4; i++)
#pragma unroll
    for (int j = 0; j < 4; j++) {
      const int col = tileN + wn * 64 + j * 16 + l15;
      const int rbase = tileM + wm * 64 + i * 16 + l4 * 4;
#pragma unroll
      for (int r = 0; r < 4; r++) {
        const int row = rbase + r;
        const size_t oidx = ((size_t)row * 64 + t) * 1024 + col;
        const float pre = acc[i][j][r] + out[oidx] + b_h[col];
        const float cand = tanh_f(pre);
        const float uu = u[row * 1024 + col];
        const float hp = h[row * 1024 + col];
        const float hn = uu * hp + (1.0f - uu) * cand;
        out[oidx] = hn;
        h[row * 1024 + col] = hn;
        hbf[row * 1024 + col] = f2bf(hn);
      }
    }
}

// --------------------------- small helper kernels ---------------------------
__global__ __launch_bounds__(256) void k_conv_txt(const float* __restrict__ x,
                                                  unsigned short* __restrict__ y) {
  const int i = blockIdx.x * 256 + threadIdx.x;  // float4 index
  const float4 v = ((const float4*)x)[i];
  uint2 o;
  o.x = (unsigned)f2bf(v.x) | ((unsigned)f2bf(v.y) << 16);
  o.y = (unsigned)f2bf(v.z) | ((unsigned)f2bf(v.w) << 16);
  ((uint2*)y)[i] = o;
}

__global__ __launch_bounds__(256) void k_conv_w(
    const float* __restrict__ Wiu, const float* __restrict__ Wir, const float* __restrict__ Wi,
    const float* __restrict__ Whu, const float* __restrict__ Whr, const float* __restrict__ Wh,
    unsigned short* __restrict__ Wx, unsigned short* __restrict__ Whh) {
  const int idx = blockIdx.x * 256 + threadIdx.x;  // 0..1572863 (2 cats * 786432)
  const int second = idx >= 786432;
  const int id = idx - (second ? 786432 : 0);
  const int n = id >> 8;            // dst row 0..3071
  const int kk = (id & 255) << 2;   // dst col (float4)
  const int sel = n >> 10, r = n & 1023;
  const float* src;
  if (second) src = (sel == 0) ? Whu : (sel == 1) ? Whr : Wh;
  else        src = (sel == 0) ? Wiu : (sel == 1) ? Wir : Wi;
  const float4 v = *(const float4*)(src + (size_t)r * 1024 + kk);
  uint2 o;
  o.x = (unsigned)f2bf(v.x) | ((unsigned)f2bf(v.y) << 16);
  o.y = (unsigned)f2bf(v.z) | ((unsigned)f2bf(v.w) << 16);
  unsigned short* dst = second ? Whh : Wx;
  *(uint2*)(dst + (size_t)n * 1024 + kk) = o;
}

__global__ __launch_bounds__(256) void k_h0(float* __restrict__ out, float* __restrict__ h,
                                            unsigned short* __restrict__ hbf) {
  const int e = blockIdx.x * 256 + threadIdx.x;  // 0..262143
  const int b = e >> 10, d = e & 1023;
  const size_t oidx = (size_t)b * 65536 + d;     // out[b][0][d] holds XPi(t=0)
  const float v = tanh_f(out[oidx]);
  out[oidx] = v;
  h[e] = v;
  hbf[e] = f2bf(v);
}

// ---------------------------------------------------------------------------
extern "C" void kernel_launch(void* const* d_in, const int* in_sizes, int n_in,
                              void* d_out, int out_size, void* d_ws, size_t ws_size,
                              hipStream_t stream) {
  const float* txt  = (const float*)d_in[0];
  const float* Wiu  = (const float*)d_in[1];
  const float* biu  = (const float*)d_in[2];
  const float* Whu  = (const float*)d_in[3];
  const float* bhu  = (const float*)d_in[4];
  const float* Wir  = (const float*)d_in[5];
  const float* bir  = (const float*)d_in[6];
  const float* Whr  = (const float*)d_in[7];
  const float* bhr  = (const float*)d_in[8];
  const float* Wi   = (const float*)d_in[9];
  const float* bi   = (const float*)d_in[10];
  const float* Wh   = (const float*)d_in[11];
  const float* bh   = (const float*)d_in[12];
  float* out = (float*)d_out;

  char* ws = (char*)d_ws;
  unsigned short* Xbf  = (unsigned short*)(ws);              //  32 MB  [16384][1024]
  unsigned short* Wx   = (unsigned short*)(ws + 33554432);   //   6 MB  [3072][1024]
  unsigned short* Whhc = (unsigned short*)(ws + 39845888);   //   6 MB  [3072][1024] (hu|hr|h)
  unsigned short* XPur = (unsigned short*)(ws + 46137344);   //  64 MB  [64][256][2048]
  float*          hbuf = (float*)(ws + 113246208);           //   1 MB  [256][1024]
  unsigned short* hbf  = (unsigned short*)(ws + 114294784);  // 0.5 MB
  float*          ubuf = (float*)(ws + 114819072);           //   1 MB
  unsigned short* rh   = (unsigned short*)(ws + 115867648);  // 0.5 MB  (total 116.4 MB)

  // 1) cast inputs to bf16 (weights concatenated)
  k_conv_txt<<<16384, 256, 0, stream>>>(txt, Xbf);
  k_conv_w<<<6144, 256, 0, stream>>>(Wiu, Wir, Wi, Whu, Whr, Wh, Wx, Whhc);

  // 2) hoisted x-projections for all 64 steps (one big MFMA GEMM)
  k_pre<<<dim3(24, 128), 256, 0, stream>>>(Xbf, Wx, XPur, out, biu, bhu, bir, bhr, bi);

  // 3) h0 = tanh(XPi[t=0]) in place
  k_h0<<<1024, 256, 0, stream>>>(out, hbuf, hbf);

  // 4) recurrence: 63 steps x (gates GEMM, candidate GEMM)
  for (int t = 1; t < 64; t++) {
    k_gates<<<dim3(16, 2), 256, 0, stream>>>(hbf, Whhc, XPur + (size_t)t * 256 * 2048,
                                             ubuf, hbuf, rh);
    k_cand<<<dim3(8, 2), 256, 0, stream>>>(rh, Whhc + 2048 * 1024, out, hbuf, hbf,
                                           ubuf, bh, t);
  }
  (void)in_sizes; (void)n_in; (void)out_size; (void)ws_size;
}